// Round 1
// 1577.198 us; speedup vs baseline: 1.2474x; 1.2474x over previous
//
#include <hip/hip_runtime.h>
#include <hip/hip_bf16.h>
#include <stdint.h>

#define B_ 16
#define T_ 1024
#define EMBED_ 128
#define HID_ 256
#define G4_ 1024
#define NC_ 8000
#define M_ (B_*T_)

typedef short bf16x8 __attribute__((ext_vector_type(8)));
typedef float f32x4 __attribute__((ext_vector_type(4)));

#if defined(__has_builtin)
#if __has_builtin(__builtin_amdgcn_sdot4)
#define SDOT4(a,b,c) __builtin_amdgcn_sdot4((a),(b),(c),false)
#endif
#endif
#ifndef SDOT4
__device__ __forceinline__ int sdot4_sw(int a, int b, int c) {
    c += (int)(signed char)(a)       * (int)(signed char)(b);
    c += (int)(signed char)(a >> 8)  * (int)(signed char)(b >> 8);
    c += (int)(signed char)(a >> 16) * (int)(signed char)(b >> 16);
    c += (int)(signed char)(a >> 24) * (int)(signed char)(b >> 24);
    return c;
}
#define SDOT4(a,b,c) sdot4_sw((a),(b),(c))
#endif

__device__ __forceinline__ float sigmoid_f(float x) {
    float e = __expf(-x);
    return __builtin_amdgcn_rcpf(1.f + e);   // x<<0: e=inf -> 0 ; x>>0: e=0 -> 1
}

// ---------------- embed + concat -> bf16 (16384 x 256) ----------------
__global__ void embed_kernel(const int* __restrict__ x,
                             const float* __restrict__ ew,
                             const float* __restrict__ lw,
                             __hip_bfloat16* __restrict__ inp) {
    int m = blockIdx.x;          // b*T + t
    int e = threadIdx.x;         // 0..255
    int i0 = x[2 * m];
    int i1 = x[2 * m + 1];
    float v = (e < EMBED_) ? ew[i0 * EMBED_ + e] : lw[i1 * EMBED_ + (e - EMBED_)];
    inp[m * 256 + e] = __float2bfloat16(v);
}

// ---------------- f32 -> bf16 ----------------
__global__ void f2bf_kernel(const float* __restrict__ in,
                            __hip_bfloat16* __restrict__ out, int n) {
    int i = blockIdx.x * blockDim.x + threadIdx.x;
    if (i < n) out[i] = __float2bfloat16(in[i]);
}

// ---------------- per-row int8 quant of W_hh (1024 rows x 256) ----------------
__global__ void quant_whh_kernel(const float* __restrict__ whh,
                                 int* __restrict__ wq, float* __restrict__ wscale) {
    int r = blockIdx.x;      // 1024
    int lane = threadIdx.x;  // 64
    float4 v = ((const float4*)(whh + r * HID_))[lane];
    float m = fmaxf(fmaxf(fabsf(v.x), fabsf(v.y)), fmaxf(fabsf(v.z), fabsf(v.w)));
    #pragma unroll
    for (int off = 32; off; off >>= 1) m = fmaxf(m, __shfl_xor(m, off, 64));
    m = fmaxf(m, 1e-20f);
    float inv = 127.f / m;
    int q0 = __float2int_rn(v.x * inv) & 255;
    int q1 = __float2int_rn(v.y * inv) & 255;
    int q2 = __float2int_rn(v.z * inv) & 255;
    int q3 = __float2int_rn(v.w * inv) & 255;
    wq[r * 64 + lane] = q0 | (q1 << 8) | (q2 << 16) | (q3 << 24);
    if (lane == 0) wscale[r] = m * (1.f / 127.f);
}

// ---------------- bf16 MFMA GEMM: C[m,n] = sum_k A[m,k]*B[n,k] + bias ----------------
// A: M x 256 (row-major, K contig), B: N x 256 (row-major, K contig)
// out_mode 0: C[m*N+n] ; out_mode 1: C[(t*16+b)*1024+n] with m=b*1024+t
__global__ __launch_bounds__(256, 4)
void gemm_bf16_kernel(const __hip_bfloat16* __restrict__ A,
                      const __hip_bfloat16* __restrict__ Bm,
                      const float* __restrict__ bias1,
                      const float* __restrict__ bias2,
                      float* __restrict__ C,
                      int N, int out_mode) {
    __shared__ short As[64][136];   // pad: row stride 272B -> 2-way bank alias (free)
    __shared__ short Bs[64][136];
    const int tid = threadIdx.x;
    const int m0 = blockIdx.y * 64;
    const int n0 = blockIdx.x * 64;
    const int w = tid >> 6;
    const int lane = tid & 63;
    const int l15 = lane & 15;
    const int q = lane >> 4;

    f32x4 zero4 = {0.f, 0.f, 0.f, 0.f};
    f32x4 acc[4] = {zero4, zero4, zero4, zero4};

    const int r = tid >> 2;
    const int cbase = tid & 3;

    for (int ko = 0; ko < 256; ko += 128) {
        #pragma unroll
        for (int i = 0; i < 4; ++i) {
            int c = cbase + (i << 2);  // 0..15 chunks of 8 elems
            uint4 av = ((const uint4*)A)[(size_t)(m0 + r) * 32 + (ko >> 3) + c];
            *((uint4*)&As[r][c * 8]) = av;
            uint4 bv = ((const uint4*)Bm)[(size_t)(n0 + r) * 32 + (ko >> 3) + c];
            *((uint4*)&Bs[r][c * 8]) = bv;
        }
        __syncthreads();
        #pragma unroll
        for (int kc = 0; kc < 4; ++kc) {
            bf16x8 af = *((const bf16x8*)&As[w * 16 + l15][kc * 32 + q * 8]);
            #pragma unroll
            for (int nt = 0; nt < 4; ++nt) {
                bf16x8 bfr = *((const bf16x8*)&Bs[nt * 16 + l15][kc * 32 + q * 8]);
                acc[nt] = __builtin_amdgcn_mfma_f32_16x16x32_bf16(af, bfr, acc[nt], 0, 0, 0);
            }
        }
        __syncthreads();
    }

    #pragma unroll
    for (int nt = 0; nt < 4; ++nt) {
        int n = n0 + nt * 16 + l15;
        float bsum = bias1[n] + (bias2 ? bias2[n] : 0.f);
        #pragma unroll
        for (int rg = 0; rg < 4; ++rg) {
            int m = m0 + w * 16 + q * 4 + rg;     // D: row m = quad*4+reg, col n = lane&15
            float val = acc[nt][rg] + bsum;
            if (out_mode == 0) {
                C[(size_t)m * N + n] = val;
            } else {
                int t = m & (T_ - 1), b = m >> 10;
                C[((size_t)((t << 4) + b) << 10) + n] = val;
            }
        }
    }
}

// ---------------- LSTM scan: 1 WG per batch, lane-paired gates, W_hh int8 in VGPRs --
// thread 2k  : rows k (i)     and 512+k (g)   of the gate matrix
// thread 2k+1: rows 256+k (f) and 768+k (o)
// partner exchange via __shfl_xor(.,1) (same wave) -> no LDS gate exchange.
// h quantized with FIXED scale 127 (|h| = |o*tanh(c)| < 1 strictly) -> no dynamic
// hmax reduction, no extra barriers. One raw s_barrier per step; no vmcnt drain,
// so the xproj prefetch and hs store stay in flight across the barrier.
__global__ __launch_bounds__(512, 2)
void lstm_scan_kernel(const int* __restrict__ wq,
                      const float* __restrict__ wscale,
                      const float* __restrict__ xproj,
                      __hip_bfloat16* __restrict__ hs) {
    __shared__ __align__(16) int h_lds[2][64];  // 256 int8 h values, double buffered

    const int tid = threadIdx.x;   // 512
    const int b = blockIdx.x;      // 16
    const int u = tid >> 1;        // hidden unit 0..255
    const int odd = tid & 1;
    const int r0 = odd ? (256 + u) : u;           // f : i
    const int r1 = odd ? (768 + u) : (512 + u);   // o : g

    // load both weight rows (2 x 256 int8 = 128 VGPRs)
    int w0[64], w1[64];
    {
        const int4* p0 = (const int4*)wq + r0 * 16;
        const int4* p1 = (const int4*)wq + r1 * 16;
        #pragma unroll
        for (int i = 0; i < 16; ++i) {
            int4 a = p0[i];
            w0[4 * i + 0] = a.x; w0[4 * i + 1] = a.y; w0[4 * i + 2] = a.z; w0[4 * i + 3] = a.w;
            int4 bb = p1[i];
            w1[4 * i + 0] = bb.x; w1[4 * i + 1] = bb.y; w1[4 * i + 2] = bb.z; w1[4 * i + 3] = bb.w;
        }
    }
    const float qs0 = wscale[r0] * (1.f / 127.f);  // weight scale * fixed h scale
    const float qs1 = wscale[r1] * (1.f / 127.f);
    // a1 = odd ? sigmoid(gb) : tanh(gb), branchless: tanh(x) = 2*sigmoid(2x)-1
    const float kb = odd ? 1.f : 2.f;
    const float mb = odd ? 1.f : 2.f;
    const float nb = odd ? 0.f : -1.f;

    if (tid < 64) h_lds[0][tid] = 0;
    float c = 0.f;
    float xp0 = xproj[(b << 10) + r0];
    float xp1 = xproj[(b << 10) + r1];
    __syncthreads();

    for (int t = 0; t < T_; ++t) {
        // prefetch next timestep's xproj (consumed after the barrier, ~1 step of cover)
        float nx0 = 0.f, nx1 = 0.f;
        if (t < T_ - 1) {
            const float* p = xproj + ((size_t)(((t + 1) << 4) + b) << 10);
            nx0 = p[r0];
            nx1 = p[r1];
        }
        int acc0 = 0, acc1 = 0;
        const int* hb = h_lds[t & 1];
        #pragma unroll
        for (int kd = 0; kd < 16; ++kd) {
            int4 hv = *((const int4*)(hb + kd * 4));   // broadcast read
            acc0 = SDOT4(w0[4 * kd + 0], hv.x, acc0);
            acc0 = SDOT4(w0[4 * kd + 1], hv.y, acc0);
            acc0 = SDOT4(w0[4 * kd + 2], hv.z, acc0);
            acc0 = SDOT4(w0[4 * kd + 3], hv.w, acc0);
            acc1 = SDOT4(w1[4 * kd + 0], hv.x, acc1);
            acc1 = SDOT4(w1[4 * kd + 1], hv.y, acc1);
            acc1 = SDOT4(w1[4 * kd + 2], hv.z, acc1);
            acc1 = SDOT4(w1[4 * kd + 3], hv.w, acc1);
        }
        float ga = (float)acc0 * qs0 + xp0;           // pre-act: i (even) / f (odd)
        float gb = (float)acc1 * qs1 + xp1;           // pre-act: g (even) / o (odd)
        float a0 = sigmoid_f(ga);                     // i / f
        float a1 = sigmoid_f(kb * gb) * mb + nb;      // g / o
        float pa0 = __shfl_xor(a0, 1, 64);            // partner's f / i
        float pa1 = __shfl_xor(a1, 1, 64);            // partner's o / g
        float iv = odd ? pa0 : a0;
        float fv = odd ? a0 : pa0;
        float gv = odd ? pa1 : a1;
        float ov = odd ? a1 : pa1;
        c = fv * c + iv * gv;                         // replicated on both lanes
        float th = 2.f * sigmoid_f(c + c) - 1.f;      // tanh(c)
        float h = ov * th;
        if (!odd) {
            hs[(((size_t)(b << 10) + t) << 8) + u] = __float2bfloat16(h);
            ((signed char*)h_lds[(t + 1) & 1])[u] =
                (signed char)__float2int_rn(h * 127.f);   // |h|<1 -> no clamp needed
        }
        // LDS-only barrier: drain ds ops, rendezvous, fence the scheduler.
        // Deliberately NO vmcnt drain (prefetch + hs store stay in flight).
        asm volatile("s_waitcnt lgkmcnt(0)" ::: "memory");
        __builtin_amdgcn_s_barrier();
        __builtin_amdgcn_sched_barrier(0);
        xp0 = nx0;
        xp1 = nx1;
    }
}

extern "C" void kernel_launch(void* const* d_in, const int* in_sizes, int n_in,
                              void* d_out, int out_size, void* d_ws, size_t ws_size,
                              hipStream_t stream) {
    const int* x            = (const int*)d_in[0];
    const float* embed_x_w  = (const float*)d_in[1];
    const float* embed_lb_w = (const float*)d_in[2];
    const float* W_ih       = (const float*)d_in[3];
    const float* W_hh       = (const float*)d_in[4];
    const float* b_ih       = (const float*)d_in[5];
    const float* b_hh       = (const float*)d_in[6];
    const float* fc_w       = (const float*)d_in[7];
    const float* fc_b       = (const float*)d_in[8];
    float* out = (float*)d_out;

    char* ws = (char*)d_ws;
    __hip_bfloat16* inp_bf = (__hip_bfloat16*)(ws);                 //  8,388,608 B
    __hip_bfloat16* wih_bf = (__hip_bfloat16*)(ws + 8388608);       //    524,288 B
    __hip_bfloat16* fcw_bf = (__hip_bfloat16*)(ws + 8912896);       //  4,096,000 B
    int*   whh_q           = (int*)(ws + 13008896);                 //    262,144 B
    float* whh_s           = (float*)(ws + 13271040);               //      4,096 B
    float* xproj           = (float*)(ws + 13275136);               // 67,108,864 B
    __hip_bfloat16* hs     = (__hip_bfloat16*)(ws + 80384000);      //  8,388,608 B
    (void)in_sizes; (void)n_in; (void)out_size; (void)ws_size;

    hipLaunchKernelGGL(embed_kernel, dim3(M_), dim3(256), 0, stream,
                       x, embed_x_w, embed_lb_w, inp_bf);
    hipLaunchKernelGGL(f2bf_kernel, dim3((G4_ * HID_ + 255) / 256), dim3(256), 0, stream,
                       W_ih, wih_bf, G4_ * HID_);
    hipLaunchKernelGGL(f2bf_kernel, dim3((NC_ * HID_ + 255) / 256), dim3(256), 0, stream,
                       fc_w, fcw_bf, NC_ * HID_);
    hipLaunchKernelGGL(quant_whh_kernel, dim3(G4_), dim3(64), 0, stream,
                       W_hh, whh_q, whh_s);
    // x_proj: (t,b,1024) = inp @ W_ih^T + b_ih + b_hh
    hipLaunchKernelGGL(gemm_bf16_kernel, dim3(G4_ / 64, M_ / 64), dim3(256), 0, stream,
                       inp_bf, wih_bf, b_ih, b_hh, xproj, G4_, 1);
    // sequential LSTM over T, one WG per batch element
    hipLaunchKernelGGL(lstm_scan_kernel, dim3(B_), dim3(512), 0, stream,
                       whh_q, whh_s, xproj, hs);
    // out: (b,t,8000) = hs @ fc_w^T + fc_b
    hipLaunchKernelGGL(gemm_bf16_kernel, dim3(NC_ / 64, M_ / 64), dim3(256), 0, stream,
                       hs, fcw_bf, fc_b, (const float*)nullptr, out, NC_, 0);
}